// Round 3
// baseline (393.573 us; speedup 1.0000x reference)
//
#include <hip/hip_runtime.h>
#include <hip/hip_fp16.h>

#define N_NODES 50000
#define HID 128
#define CLS 64

#define NBINS 196        // ceil(50000/256) node bins
#define NBLK 256         // hist/scatter blocks
#define LBUF_CAP 4096    // per-bin CSR staging (bin degree ~3277 + 14 sigma)
#define WTOT 57344       // 3*128*128 + 64*128 weight elements
#define GEMM0_BLOCKS 782 // ceil(3125 tiles / 4 waves)
#define AGG_BLOCKS 12500 // 3125 dst tiles x 4 column slices
#define GEMMF_BLOCKS 782 // ceil(3125 tiles / 4 waves)

typedef __attribute__((ext_vector_type(8))) _Float16 f16x8;
typedef __attribute__((ext_vector_type(4))) float f32x4;

// ---------------- K1: per-(block,bin) histogram + W split ----------------
__global__ __launch_bounds__(256) void hist_wsplit_kernel(
    const int* __restrict__ col, int* __restrict__ hist,
    const float* __restrict__ W0, const float* __restrict__ W1,
    const float* __restrict__ W2, const float* __restrict__ Wl,
    __half* __restrict__ o0h, __half* __restrict__ o0l,
    __half* __restrict__ o1h, __half* __restrict__ o1l,
    __half* __restrict__ o2h, __half* __restrict__ o2l,
    __half* __restrict__ o3h, __half* __restrict__ o3l,
    int E, int chunk) {
    int widx = blockIdx.x * 256 + threadIdx.x;
    if (widx < WTOT) {
        const float* W;
        __half *oh, *ol;
        int NCdim, local;
        if (widx < 16384)      { W = W0; oh = o0h; ol = o0l; NCdim = 128; local = widx; }
        else if (widx < 32768) { W = W1; oh = o1h; ol = o1l; NCdim = 128; local = widx - 16384; }
        else if (widx < 49152) { W = W2; oh = o2h; ol = o2l; NCdim = 128; local = widx - 32768; }
        else                   { W = Wl; oh = o3h; ol = o3l; NCdim = 64;  local = widx - 49152; }
        int nn = local >> 7;
        int k = local & 127;
        float v = W[(size_t)k * NCdim + nn];
        __half h = __float2half_rn(v);
        oh[local] = h;
        ol[local] = __float2half_rn(v - __half2float(h));
    }
    __shared__ int h[NBINS];
    for (int i = threadIdx.x; i < NBINS; i += 256) h[i] = 0;
    __syncthreads();
    int b = blockIdx.x;
    int beg = b * chunk;
    int end = min(E, beg + chunk);
    if (beg < end) {
        int vend = beg + ((end - beg) & ~3);
        for (int i = beg + threadIdx.x * 4; i < vend; i += 1024) {
            int4 c4 = *(const int4*)(col + i);
            atomicAdd(&h[c4.x >> 8], 1);
            atomicAdd(&h[c4.y >> 8], 1);
            atomicAdd(&h[c4.z >> 8], 1);
            atomicAdd(&h[c4.w >> 8], 1);
        }
        int i = vend + threadIdx.x;
        if (i < end) atomicAdd(&h[col[i] >> 8], 1);
    }
    __syncthreads();
    for (int i = threadIdx.x; i < NBINS; i += 256)
        hist[i * NBLK + b] = h[i];  // bin-major, block-minor
}

// ---------------- K2: scatter (self-computed cursors; binBase published) ----------
__global__ __launch_bounds__(256) void scatter_kernel(
    const int* __restrict__ row, const int* __restrict__ col,
    const int* __restrict__ hist, int* __restrict__ binBase_g,
    int* __restrict__ sbuf_src, unsigned char* __restrict__ sbuf_c,
    int E, int chunk) {
    __shared__ int sTot[256];
    __shared__ int cur[NBINS];
    int b = blockIdx.x, t = threadIdx.x;
    int partial = 0, total = 0;
    if (t < NBINS) {
        const int4* r4 = (const int4*)(hist + t * NBLK);
        int nb4 = b >> 2, rem = b & 3;
        for (int j = 0; j < NBLK / 4; ++j) {
            int4 v = r4[j];
            int s = v.x + v.y + v.z + v.w;
            total += s;
            if (j < nb4) partial += s;
            else if (j == nb4) {
                if (rem > 0) partial += v.x;
                if (rem > 1) partial += v.y;
                if (rem > 2) partial += v.z;
            }
        }
    }
    sTot[t] = (t < NBINS) ? total : 0;
    __syncthreads();
#pragma unroll
    for (int off = 1; off < 256; off <<= 1) {
        int u = (t >= off) ? sTot[t - off] : 0;
        __syncthreads();
        sTot[t] += u;
        __syncthreads();
    }
    int myBase = sTot[t] - total;  // exclusive scan value for bin t
    if (t < NBINS) cur[t] = myBase + partial;
    if (b == 0) {
        if (t < NBINS) binBase_g[t] = myBase;
        if (t == 0) binBase_g[NBINS] = E;
    }
    __syncthreads();
    int beg = b * chunk;
    int end = min(E, beg + chunk);
    if (beg >= end) return;
    int vend = beg + ((end - beg) & ~3);
    for (int i = beg + t * 4; i < vend; i += 1024) {
        int4 c4 = *(const int4*)(col + i);
        int4 r4 = *(const int4*)(row + i);
        int p;
        p = atomicAdd(&cur[c4.x >> 8], 1); sbuf_src[p] = r4.x; sbuf_c[p] = (unsigned char)(c4.x & 255);
        p = atomicAdd(&cur[c4.y >> 8], 1); sbuf_src[p] = r4.y; sbuf_c[p] = (unsigned char)(c4.y & 255);
        p = atomicAdd(&cur[c4.z >> 8], 1); sbuf_src[p] = r4.z; sbuf_c[p] = (unsigned char)(c4.z & 255);
        p = atomicAdd(&cur[c4.w >> 8], 1); sbuf_src[p] = r4.w; sbuf_c[p] = (unsigned char)(c4.w & 255);
    }
    int i = vend + t;
    if (i < end) {
        int c = col[i];
        int p = atomicAdd(&cur[c >> 8], 1);
        sbuf_src[p] = row[i];
        sbuf_c[p] = (unsigned char)(c & 255);
    }
}

// ---------------- GEMM body for gemm-0 (A = x fp32, in-register convert) ----------
__device__ __forceinline__ void gemm0_body(
    const float* __restrict__ x, const __half* __restrict__ Bh,
    const __half* __restrict__ Bl, __half* __restrict__ C, int M, int rowTile) {
    constexpr int NT = 8;
    int lane = threadIdx.x & 63;
    int m0 = rowTile << 4;
    if (m0 >= M) return;
    int mr = lane & 15;
    int kq = (lane >> 4) << 3;

    const float*  af = x + (size_t)(m0 + mr) * 128 + kq;
    const __half* bh = Bh + (size_t)mr * 128 + kq;
    const __half* bl = Bl + (size_t)mr * 128 + kq;

    f32x4 acc[NT];
#pragma unroll
    for (int t = 0; t < NT; ++t) acc[t] = (f32x4){0.f, 0.f, 0.f, 0.f};
#pragma unroll
    for (int kc = 0; kc < 128; kc += 32) {
        float4 lo = *(const float4*)(af + kc);
        float4 hi = *(const float4*)(af + kc + 4);
        f16x8 a;
        a[0] = (_Float16)lo.x; a[1] = (_Float16)lo.y;
        a[2] = (_Float16)lo.z; a[3] = (_Float16)lo.w;
        a[4] = (_Float16)hi.x; a[5] = (_Float16)hi.y;
        a[6] = (_Float16)hi.z; a[7] = (_Float16)hi.w;
#pragma unroll
        for (int t = 0; t < NT; ++t) {
            f16x8 wh = *(const f16x8*)(bh + (size_t)t * 16 * 128 + kc);
            f16x8 wl = *(const f16x8*)(bl + (size_t)t * 16 * 128 + kc);
            acc[t] = __builtin_amdgcn_mfma_f32_16x16x32_f16(a, wh, acc[t], 0, 0, 0);
            acc[t] = __builtin_amdgcn_mfma_f32_16x16x32_f16(a, wl, acc[t], 0, 0, 0);
        }
    }
    int r0 = m0 + ((lane >> 4) << 2);
    int cc = lane & 15;
#pragma unroll
    for (int t = 0; t < NT; ++t)
#pragma unroll
        for (int r = 0; r < 4; ++r)
            C[(size_t)(r0 + r) * 128 + t * 16 + cc] =
                __float2half_rn(acc[t][r]);
}

// ---------------- K3: fused csr_place (blocks < NBINS) + GEMM-0 (rest) ------------
// csr_src now u16 (N=50000 < 65536) to shrink the per-slice csr re-read.
__global__ __launch_bounds__(256) void csrplace_gemm0_kernel(
    const int* __restrict__ binBase,
    const int* __restrict__ sbuf_src, const unsigned char* __restrict__ sbuf_c,
    float* __restrict__ dinv, int* __restrict__ row_ptr,
    unsigned short* __restrict__ csr_src,
    const float* __restrict__ x, const __half* __restrict__ W0h,
    const __half* __restrict__ W0l, __half* __restrict__ h2, int n, int E) {
    __shared__ int lcnt[256];
    __shared__ int lcur[256];
    __shared__ int ss[256];
    __shared__ int lbuf[LBUF_CAP];
    int b = blockIdx.x;
    if (b >= NBINS) {
        gemm0_body(x, W0h, W0l, h2, n, (b - NBINS) * 4 + (threadIdx.x >> 6));
        return;
    }
    int t = threadIdx.x;
    lcnt[t] = 0;
    __syncthreads();
    int beg = binBase[b], end = binBase[b + 1];
    for (int j = beg + t; j < end; j += 256)
        atomicAdd(&lcnt[sbuf_c[j]], 1);
    __syncthreads();
    int deg = lcnt[t];
    int node = b * 256 + t;
    if (node < n) dinv[node] = rsqrtf((float)deg + 1.0f);
    ss[t] = deg;
    __syncthreads();
#pragma unroll
    for (int off = 1; off < 256; off <<= 1) {
        int u = (t >= off) ? ss[t - off] : 0;
        __syncthreads();
        ss[t] += u;
        __syncthreads();
    }
    int excl = ss[t] - deg;
    lcur[t] = excl;
    int total = ss[255];
    if (node < n) row_ptr[node] = beg + excl;
    if (b == 0 && t == 0) row_ptr[n] = E;
    __syncthreads();
    for (int j = beg + t; j < end; j += 256) {
        int c = sbuf_c[j];
        int pos = atomicAdd(&lcur[c], 1);
        lbuf[pos] = sbuf_src[j];
    }
    __syncthreads();
    for (int j = t; j < total; j += 256)
        csr_src[beg + j] = (unsigned short)lbuf[j];
}

// ---------------- K_agg: XCD-sliced aggregation (de-fused) ----------------
// Block b: slice s = b&3 (32 cols = one 64B line), dst tile = b>>2 (16 nodes).
// With blockIdx%8 XCD round-robin, slice s lands only on XCDs {s, s+4} ->
// per-XCD gather working set = N*64B = 3.2MB, fits the 4MB XCD L2.
// 16-lane group per node; lane covers 2 cols (half2, 4B). Edge indices via
// same-address u16 loads (1 transaction/group), w = dinv[src]*dinv[dst] exact
// fp32 via same-address L2-resident gather. Batch-of-8 pipelined loads.
// Output h_act written nontemporal so the write stream doesn't evict the slice.
__global__ __launch_bounds__(256) void agg_slice_kernel(
    const __half* __restrict__ h2, const int* __restrict__ row_ptr,
    const unsigned short* __restrict__ csr_src, const float* __restrict__ dinv,
    const float* __restrict__ bias, __half* __restrict__ hout, int n) {
    int b = blockIdx.x;
    int s = b & 3;           // column slice
    int tile = b >> 2;       // dst tile
    int t = threadIdx.x;
    int grp = t >> 4;        // node group 0..15
    int l16 = t & 15;
    int wid = tile * 16 + grp;
    if (wid >= n) return;
    int cOff = (s << 5) + (l16 << 1);     // column (halves)
    int hvo = (s << 4) + l16;             // column (half2 units), 0..63
    const __half2* hv = (const __half2*)h2;

    int base = row_ptr[wid];
    int deg = row_ptr[wid + 1] - base;
    float dv = dinv[wid];
    float ax = 0.f, ay = 0.f;

    for (int j0 = 0; j0 < deg; j0 += 8) {
        int sidx[8];
#pragma unroll
        for (int p = 0; p < 8; ++p) {
            int jj = j0 + p;
            sidx[p] = csr_src[base + (jj < deg ? jj : deg - 1)];
        }
        float wv[8];
#pragma unroll
        for (int p = 0; p < 8; ++p)
            wv[p] = (j0 + p < deg) ? dinv[sidx[p]] * dv : 0.f;
        __half2 r[8];
#pragma unroll
        for (int p = 0; p < 8; ++p)
            r[p] = hv[((size_t)sidx[p] << 6) + hvo];
#pragma unroll
        for (int p = 0; p < 8; ++p) {
            float2 v = __half22float2(r[p]);
            ax = fmaf(v.x, wv[p], ax);
            ay = fmaf(v.y, wv[p], ay);
        }
    }
    float sn = dv * dv;
    float2 self = __half22float2(hv[((size_t)wid << 6) + hvo]);
    float2 bb = *(const float2*)(bias + cOff);
    float ox = fmaxf(fmaf(self.x, sn, ax) + bb.x, 0.f);
    float oy = fmaxf(fmaf(self.y, sn, ay) + bb.y, 0.f);
    __half2 pk = __float22half2_rn(make_float2(ox, oy));
    unsigned int pkbits;
    __builtin_memcpy(&pkbits, &pk, 4);
    __builtin_nontemporal_store(pkbits,
                                (unsigned int*)hout + ((size_t)wid << 6) + hvo);
}

// ---------------- K_gemm: fp16 GEMM, in-place safe ----------------
// One 16-row tile per wave, full NC cols. A-frags hoisted before any store and
// each wave writes only the rows it read -> A may alias C (no __restrict__).
template<int NC, bool HEAD>
__global__ __launch_bounds__(256) void gemm_f16_kernel(
    const __half* A, const __half* __restrict__ Bh, const __half* __restrict__ Bl,
    const float* __restrict__ gbias, void* Cv, int n) {
    constexpr int NT = NC / 16;
    int wave = threadIdx.x >> 6;
    int lane = threadIdx.x & 63;
    int m0 = (blockIdx.x * 4 + wave) << 4;
    if (m0 >= n) return;
    int mr = lane & 15;
    int kq = (lane >> 4) << 3;

    f16x8 a[4];
#pragma unroll
    for (int kc = 0; kc < 4; ++kc)
        a[kc] = *(const f16x8*)(A + (size_t)(m0 + mr) * 128 + kq + kc * 32);

    const __half* bh = Bh + (size_t)mr * 128 + kq;
    const __half* bl = Bl + (size_t)mr * 128 + kq;

    f32x4 acc[NT];
#pragma unroll
    for (int t = 0; t < NT; ++t) acc[t] = (f32x4){0.f, 0.f, 0.f, 0.f};
#pragma unroll
    for (int kc = 0; kc < 4; ++kc) {
#pragma unroll
        for (int t = 0; t < NT; ++t) {
            f16x8 wh = *(const f16x8*)(bh + (size_t)t * 16 * 128 + kc * 32);
            f16x8 wl = *(const f16x8*)(bl + (size_t)t * 16 * 128 + kc * 32);
            acc[t] = __builtin_amdgcn_mfma_f32_16x16x32_f16(a[kc], wh, acc[t], 0, 0, 0);
            acc[t] = __builtin_amdgcn_mfma_f32_16x16x32_f16(a[kc], wl, acc[t], 0, 0, 0);
        }
    }
    int r0 = m0 + ((lane >> 4) << 2);
    int cc = lane & 15;
#pragma unroll
    for (int t = 0; t < NT; ++t) {
        float bsv = HEAD ? gbias[t * 16 + cc] : 0.f;
#pragma unroll
        for (int r = 0; r < 4; ++r) {
            if (r0 + r >= n) break;
            size_t idx = (size_t)(r0 + r) * NC + t * 16 + cc;
            float val = acc[t][r] + bsv;
            if (HEAD) {
                ((float*)Cv)[idx] = val;
            } else {
                __half hv = __float2half_rn(val);
                unsigned short hb;
                __builtin_memcpy(&hb, &hv, 2);
                __builtin_nontemporal_store(hb, (unsigned short*)Cv + idx);
            }
        }
    }
}

extern "C" void kernel_launch(void* const* d_in, const int* in_sizes, int n_in,
                              void* d_out, int out_size, void* d_ws, size_t ws_size,
                              hipStream_t stream) {
    const float* x  = (const float*)d_in[0];
    const int* ei   = (const int*)d_in[1];
    const float* W0 = (const float*)d_in[2];
    const float* b0 = (const float*)d_in[3];
    const float* W1 = (const float*)d_in[4];
    const float* b1 = (const float*)d_in[5];
    const float* W2 = (const float*)d_in[6];
    const float* b2 = (const float*)d_in[7];
    const float* Wl = (const float*)d_in[8];
    const float* bl = (const float*)d_in[9];
    float* out = (float*)d_out;

    const int N = N_NODES;
    const int E = in_sizes[1] / 2;
    const int* row = ei;
    const int* col = ei + E;
    const int chunk = (((E + NBLK - 1) / NBLK) + 3) & ~3;  // 4-aligned chunks

    char* ws = (char*)d_ws;
    auto alloc = [&](size_t bytes) {
        char* p = ws;
        ws += (bytes + 255) & ~(size_t)255;
        return p;
    };
    int*   hist    = (int*)alloc((size_t)NBINS * NBLK * 4);
    int*   binBase = (int*)alloc((size_t)(NBINS + 1) * 4);
    int*   sbuf_src= (int*)alloc((size_t)E * 4);
    unsigned char* sbuf_c = (unsigned char*)alloc((size_t)E);
    int*   row_ptr = (int*)alloc((size_t)(N + 1) * 4);
    float* dinv    = (float*)alloc((size_t)N * 4);
    unsigned short* csr_src = (unsigned short*)alloc((size_t)E * 2);
    __half* h2a    = (__half*)alloc((size_t)N * HID * 2);
    __half* h2b    = (__half*)alloc((size_t)N * HID * 2);
    __half* Wt_h[4];
    __half* Wt_l[4];
    for (int i = 0; i < 3; ++i) {
        Wt_h[i] = (__half*)alloc((size_t)HID * HID * 2);
        Wt_l[i] = (__half*)alloc((size_t)HID * HID * 2);
    }
    Wt_h[3] = (__half*)alloc((size_t)CLS * HID * 2);
    Wt_l[3] = (__half*)alloc((size_t)CLS * HID * 2);

    // K1: histogram + weight split
    hist_wsplit_kernel<<<NBLK, 256, 0, stream>>>(col, hist, W0, W1, W2, Wl,
        Wt_h[0], Wt_l[0], Wt_h[1], Wt_l[1], Wt_h[2], Wt_l[2], Wt_h[3], Wt_l[3], E, chunk);
    // K2: bin-sorted scatter (self-computed cursors)
    scatter_kernel<<<NBLK, 256, 0, stream>>>(row, col, hist, binBase, sbuf_src, sbuf_c, E, chunk);
    // K3: CSR placement fused with GEMM-0 (independent workloads)
    csrplace_gemm0_kernel<<<NBINS + GEMM0_BLOCKS, 256, 0, stream>>>(
        binBase, sbuf_src, sbuf_c, dinv, row_ptr, csr_src,
        x, Wt_h[0], Wt_l[0], h2a, N, E);

    // Layer 1: sliced agg(h2a) -> h2b, then in-place GEMM@W1 on h2b
    agg_slice_kernel<<<AGG_BLOCKS, 256, 0, stream>>>(
        h2a, row_ptr, csr_src, dinv, b0, h2b, N);
    gemm_f16_kernel<128, false><<<GEMMF_BLOCKS, 256, 0, stream>>>(
        h2b, Wt_h[1], Wt_l[1], nullptr, h2b, N);
    // Layer 2: sliced agg(h2b) -> h2a, then in-place GEMM@W2 on h2a
    agg_slice_kernel<<<AGG_BLOCKS, 256, 0, stream>>>(
        h2b, row_ptr, csr_src, dinv, b1, h2a, N);
    gemm_f16_kernel<128, false><<<GEMMF_BLOCKS, 256, 0, stream>>>(
        h2a, Wt_h[2], Wt_l[2], nullptr, h2a, N);
    // Layer 3: sliced agg(h2a) -> h2b, then head GEMM@Wl -> out (fp32)
    agg_slice_kernel<<<AGG_BLOCKS, 256, 0, stream>>>(
        h2a, row_ptr, csr_src, dinv, b2, h2b, N);
    gemm_f16_kernel<64, true><<<GEMMF_BLOCKS, 256, 0, stream>>>(
        h2b, Wt_h[3], Wt_l[3], bl, out, N);
}

// Round 4
// 265.644 us; speedup vs baseline: 1.4816x; 1.4816x over previous
//
#include <hip/hip_runtime.h>
#include <hip/hip_fp16.h>

#define N_NODES 50000
#define HID 128
#define CLS 64

#define NBINS 196        // ceil(50000/256) node bins
#define NBLK 256         // hist/scatter blocks
#define LBUF_CAP 4096    // per-bin CSR staging (bin degree ~3277 + 14 sigma)
#define WTOT 57344       // 3*128*128 + 64*128 weight elements
#define GEMM0_BLOCKS 782 // ceil(3125 tiles / 4 waves)
#define AROW 136         // LDS row stride (128 + 8 pad -> 2-way bank aliasing, free)

typedef __attribute__((ext_vector_type(8))) _Float16 f16x8;
typedef __attribute__((ext_vector_type(4))) float f32x4;

// ---------------- K1: per-(block,bin) histogram + W split ----------------
__global__ __launch_bounds__(256) void hist_wsplit_kernel(
    const int* __restrict__ col, int* __restrict__ hist,
    const float* __restrict__ W0, const float* __restrict__ W1,
    const float* __restrict__ W2, const float* __restrict__ Wl,
    __half* __restrict__ o0h, __half* __restrict__ o0l,
    __half* __restrict__ o1h, __half* __restrict__ o1l,
    __half* __restrict__ o2h, __half* __restrict__ o2l,
    __half* __restrict__ o3h, __half* __restrict__ o3l,
    int E, int chunk) {
    int widx = blockIdx.x * 256 + threadIdx.x;
    if (widx < WTOT) {
        const float* W;
        __half *oh, *ol;
        int NCdim, local;
        if (widx < 16384)      { W = W0; oh = o0h; ol = o0l; NCdim = 128; local = widx; }
        else if (widx < 32768) { W = W1; oh = o1h; ol = o1l; NCdim = 128; local = widx - 16384; }
        else if (widx < 49152) { W = W2; oh = o2h; ol = o2l; NCdim = 128; local = widx - 32768; }
        else                   { W = Wl; oh = o3h; ol = o3l; NCdim = 64;  local = widx - 49152; }
        int nn = local >> 7;
        int k = local & 127;
        float v = W[(size_t)k * NCdim + nn];
        __half h = __float2half_rn(v);
        oh[local] = h;
        ol[local] = __float2half_rn(v - __half2float(h));
    }
    __shared__ int h[NBINS];
    for (int i = threadIdx.x; i < NBINS; i += 256) h[i] = 0;
    __syncthreads();
    int b = blockIdx.x;
    int beg = b * chunk;
    int end = min(E, beg + chunk);
    if (beg < end) {
        int vend = beg + ((end - beg) & ~3);
        for (int i = beg + threadIdx.x * 4; i < vend; i += 1024) {
            int4 c4 = *(const int4*)(col + i);
            atomicAdd(&h[c4.x >> 8], 1);
            atomicAdd(&h[c4.y >> 8], 1);
            atomicAdd(&h[c4.z >> 8], 1);
            atomicAdd(&h[c4.w >> 8], 1);
        }
        int i = vend + threadIdx.x;
        if (i < end) atomicAdd(&h[col[i] >> 8], 1);
    }
    __syncthreads();
    for (int i = threadIdx.x; i < NBINS; i += 256)
        hist[i * NBLK + b] = h[i];  // bin-major, block-minor
}

// ---------------- K1.5: per-bin scan over blocks ----------------
// One block per bin: exclusive-scan the bin's 256 per-block counts.
// Replaces the 200KB-per-block hist rescan that every scatter block did.
__global__ __launch_bounds__(256) void binscan_kernel(
    const int* __restrict__ hist, int* __restrict__ cursorBase,
    int* __restrict__ binTotal) {
    __shared__ int ss[256];
    int bin = blockIdx.x, t = threadIdx.x;
    int v = hist[bin * NBLK + t];
    ss[t] = v;
    __syncthreads();
#pragma unroll
    for (int off = 1; off < 256; off <<= 1) {
        int u = (t >= off) ? ss[t - off] : 0;
        __syncthreads();
        ss[t] += u;
        __syncthreads();
    }
    cursorBase[bin * NBLK + t] = ss[t] - v;   // exclusive over blocks
    if (t == 255) binTotal[bin] = ss[255];
}

// ---------------- K2: scatter (cursors from precomputed scan) ----------
__global__ __launch_bounds__(256) void scatter_kernel(
    const int* __restrict__ row, const int* __restrict__ col,
    const int* __restrict__ binTotal, const int* __restrict__ cursorBase,
    int* __restrict__ binBase_g,
    unsigned short* __restrict__ sbuf_src, unsigned char* __restrict__ sbuf_c,
    int E, int chunk) {
    __shared__ int ss[256];
    __shared__ int cur[NBINS];
    int b = blockIdx.x, t = threadIdx.x;
    int v = (t < NBINS) ? binTotal[t] : 0;
    ss[t] = v;
    __syncthreads();
#pragma unroll
    for (int off = 1; off < 256; off <<= 1) {
        int u = (t >= off) ? ss[t - off] : 0;
        __syncthreads();
        ss[t] += u;
        __syncthreads();
    }
    int myBase = ss[t] - v;  // exclusive scan value for bin t
    if (t < NBINS) cur[t] = myBase + cursorBase[t * NBLK + b];
    if (b == 0) {
        if (t < NBINS) binBase_g[t] = myBase;
        if (t == 0) binBase_g[NBINS] = E;
    }
    __syncthreads();
    int beg = b * chunk;
    int end = min(E, beg + chunk);
    if (beg >= end) return;
    int vend = beg + ((end - beg) & ~3);
    for (int i = beg + t * 4; i < vend; i += 1024) {
        int4 c4 = *(const int4*)(col + i);
        int4 r4 = *(const int4*)(row + i);
        int p;
        p = atomicAdd(&cur[c4.x >> 8], 1); sbuf_src[p] = (unsigned short)r4.x; sbuf_c[p] = (unsigned char)(c4.x & 255);
        p = atomicAdd(&cur[c4.y >> 8], 1); sbuf_src[p] = (unsigned short)r4.y; sbuf_c[p] = (unsigned char)(c4.y & 255);
        p = atomicAdd(&cur[c4.z >> 8], 1); sbuf_src[p] = (unsigned short)r4.z; sbuf_c[p] = (unsigned char)(c4.z & 255);
        p = atomicAdd(&cur[c4.w >> 8], 1); sbuf_src[p] = (unsigned short)r4.w; sbuf_c[p] = (unsigned char)(c4.w & 255);
    }
    int i = vend + t;
    if (i < end) {
        int c = col[i];
        int p = atomicAdd(&cur[c >> 8], 1);
        sbuf_src[p] = (unsigned short)row[i];
        sbuf_c[p] = (unsigned char)(c & 255);
    }
}

// ---------------- GEMM body for gemm-0 (A = x fp32, in-register convert) ----------
__device__ __forceinline__ void gemm0_body(
    const float* __restrict__ x, const __half* __restrict__ Bh,
    const __half* __restrict__ Bl, __half* __restrict__ C, int M, int rowTile) {
    constexpr int NT = 8;
    int lane = threadIdx.x & 63;
    int m0 = rowTile << 4;
    if (m0 >= M) return;
    int mr = lane & 15;
    int kq = (lane >> 4) << 3;

    const float*  af = x + (size_t)(m0 + mr) * 128 + kq;
    const __half* bh = Bh + (size_t)mr * 128 + kq;
    const __half* bl = Bl + (size_t)mr * 128 + kq;

    f32x4 acc[NT];
#pragma unroll
    for (int t = 0; t < NT; ++t) acc[t] = (f32x4){0.f, 0.f, 0.f, 0.f};
#pragma unroll
    for (int kc = 0; kc < 128; kc += 32) {
        float4 lo = *(const float4*)(af + kc);
        float4 hi = *(const float4*)(af + kc + 4);
        f16x8 a;
        a[0] = (_Float16)lo.x; a[1] = (_Float16)lo.y;
        a[2] = (_Float16)lo.z; a[3] = (_Float16)lo.w;
        a[4] = (_Float16)hi.x; a[5] = (_Float16)hi.y;
        a[6] = (_Float16)hi.z; a[7] = (_Float16)hi.w;
#pragma unroll
        for (int t = 0; t < NT; ++t) {
            f16x8 wh = *(const f16x8*)(bh + (size_t)t * 16 * 128 + kc);
            f16x8 wl = *(const f16x8*)(bl + (size_t)t * 16 * 128 + kc);
            acc[t] = __builtin_amdgcn_mfma_f32_16x16x32_f16(a, wh, acc[t], 0, 0, 0);
            acc[t] = __builtin_amdgcn_mfma_f32_16x16x32_f16(a, wl, acc[t], 0, 0, 0);
        }
    }
    int r0 = m0 + ((lane >> 4) << 2);
    int cc = lane & 15;
#pragma unroll
    for (int t = 0; t < NT; ++t)
#pragma unroll
        for (int r = 0; r < 4; ++r)
            C[(size_t)(r0 + r) * 128 + t * 16 + cc] =
                __float2half_rn(acc[t][r]);
}

// ---------------- K3: fused csr_place (blocks < NBINS) + GEMM-0 (rest) ------------
__global__ __launch_bounds__(256) void csrplace_gemm0_kernel(
    const int* __restrict__ binBase,
    const unsigned short* __restrict__ sbuf_src, const unsigned char* __restrict__ sbuf_c,
    float* __restrict__ dinv, int* __restrict__ row_ptr,
    unsigned short* __restrict__ csr_src,
    const float* __restrict__ x, const __half* __restrict__ W0h,
    const __half* __restrict__ W0l, __half* __restrict__ h2, int n, int E) {
    __shared__ int lcnt[256];
    __shared__ int lcur[256];
    __shared__ int ss[256];
    __shared__ int lbuf[LBUF_CAP];
    int b = blockIdx.x;
    if (b >= NBINS) {
        gemm0_body(x, W0h, W0l, h2, n, (b - NBINS) * 4 + (threadIdx.x >> 6));
        return;
    }
    int t = threadIdx.x;
    lcnt[t] = 0;
    __syncthreads();
    int beg = binBase[b], end = binBase[b + 1];
    for (int j = beg + t; j < end; j += 256)
        atomicAdd(&lcnt[sbuf_c[j]], 1);
    __syncthreads();
    int deg = lcnt[t];
    int node = b * 256 + t;
    if (node < n) dinv[node] = rsqrtf((float)deg + 1.0f);
    ss[t] = deg;
    __syncthreads();
#pragma unroll
    for (int off = 1; off < 256; off <<= 1) {
        int u = (t >= off) ? ss[t - off] : 0;
        __syncthreads();
        ss[t] += u;
        __syncthreads();
    }
    int excl = ss[t] - deg;
    lcur[t] = excl;
    int total = ss[255];
    if (node < n) row_ptr[node] = beg + excl;
    if (b == 0 && t == 0) row_ptr[n] = E;
    __syncthreads();
    for (int j = beg + t; j < end; j += 256) {
        int c = sbuf_c[j];
        int pos = atomicAdd(&lcur[c], 1);
        lbuf[pos] = sbuf_src[j];
    }
    __syncthreads();
    for (int j = t; j < total; j += 256)
        csr_src[beg + j] = (unsigned short)lbuf[j];
}

// ---------------- fused agg + GEMM: 16 nodes per block (R1 verified) ---------
// Phase A: 4 waves x 4 groups; each 16-lane group owns one node. The group
// gathers full 256B h2 rows as 16 lanes x f16x8 (global_load_dwordx4),
// unrolled 4-deep; nodes in parallel. relu'd fp16 rows land in LDS.
// Phase B: same waves run the 16-row MFMA tile against W (NC cols).
template<int NC, bool HEAD>
__global__ __launch_bounds__(256) void agg_gemm_kernel(
    const __half* __restrict__ h2, const int* __restrict__ row_ptr,
    const unsigned short* __restrict__ csr_src, const float* __restrict__ dinv,
    const float* __restrict__ bias,
    const __half* __restrict__ Bh, const __half* __restrict__ Bl,
    const float* __restrict__ gbias, void* __restrict__ Cv, int n) {
    __shared__ __half Als[16][AROW];
    int wave = threadIdx.x >> 6;
    int lane = threadIdx.x & 63;
    int m0 = blockIdx.x << 4;

    // ---- Phase A: one node per 16-lane group ----
    int g = lane >> 4;          // group in wave
    int l16 = lane & 15;        // lane in group
    int baseLane = lane & 48;   // first lane of this group
    int lr = (wave << 2) + g;   // local row 0..15
    int wid = m0 + lr;
    const __half* hrow = h2 + (l16 << 3);  // this lane's 8-col slice of any row

    if (wid < n) {
        int beg = row_ptr[wid];
        int end = row_ptr[wid + 1];
        float dv = dinv[wid];
        float acc[8];
#pragma unroll
        for (int i = 0; i < 8; ++i) acc[i] = 0.f;

        for (int base = beg; base < end; base += 16) {
            int cnt = end - base;
            if (cnt > 16) cnt = 16;
            int msrc = 0;
            float mw = 0.f;
            if (l16 < cnt) {
                msrc = csr_src[base + l16];
                mw = dinv[msrc] * dv;
            }
            int j = 0;
            for (; j + 4 <= cnt; j += 4) {
                int s0 = __shfl(msrc, baseLane + j);
                int s1 = __shfl(msrc, baseLane + j + 1);
                int s2 = __shfl(msrc, baseLane + j + 2);
                int s3 = __shfl(msrc, baseLane + j + 3);
                float w0 = __shfl(mw, baseLane + j);
                float w1 = __shfl(mw, baseLane + j + 1);
                float w2 = __shfl(mw, baseLane + j + 2);
                float w3 = __shfl(mw, baseLane + j + 3);
                f16x8 v0 = *(const f16x8*)(hrow + ((size_t)s0 << 7));
                f16x8 v1 = *(const f16x8*)(hrow + ((size_t)s1 << 7));
                f16x8 v2 = *(const f16x8*)(hrow + ((size_t)s2 << 7));
                f16x8 v3 = *(const f16x8*)(hrow + ((size_t)s3 << 7));
#pragma unroll
                for (int i = 0; i < 8; ++i) {
                    acc[i] = fmaf((float)v0[i], w0, acc[i]);
                    acc[i] = fmaf((float)v1[i], w1, acc[i]);
                    acc[i] = fmaf((float)v2[i], w2, acc[i]);
                    acc[i] = fmaf((float)v3[i], w3, acc[i]);
                }
            }
            for (; j + 2 <= cnt; j += 2) {
                int s0 = __shfl(msrc, baseLane + j);
                int s1 = __shfl(msrc, baseLane + j + 1);
                float w0 = __shfl(mw, baseLane + j);
                float w1 = __shfl(mw, baseLane + j + 1);
                f16x8 v0 = *(const f16x8*)(hrow + ((size_t)s0 << 7));
                f16x8 v1 = *(const f16x8*)(hrow + ((size_t)s1 << 7));
#pragma unroll
                for (int i = 0; i < 8; ++i) {
                    acc[i] = fmaf((float)v0[i], w0, acc[i]);
                    acc[i] = fmaf((float)v1[i], w1, acc[i]);
                }
            }
            if (j < cnt) {
                int s0 = __shfl(msrc, baseLane + j);
                float w0 = __shfl(mw, baseLane + j);
                f16x8 v0 = *(const f16x8*)(hrow + ((size_t)s0 << 7));
#pragma unroll
                for (int i = 0; i < 8; ++i)
                    acc[i] = fmaf((float)v0[i], w0, acc[i]);
            }
        }
        // self loop + bias + relu -> fp16 row in LDS
        float sn = dv * dv;
        f16x8 sv = *(const f16x8*)(hrow + ((size_t)wid << 7));
        float4 ba = *(const float4*)(bias + (l16 << 3));
        float4 bb = *(const float4*)(bias + (l16 << 3) + 4);
        float o[8];
#pragma unroll
        for (int i = 0; i < 8; ++i) o[i] = fmaf((float)sv[i], sn, acc[i]);
        o[0] += ba.x; o[1] += ba.y; o[2] += ba.z; o[3] += ba.w;
        o[4] += bb.x; o[5] += bb.y; o[6] += bb.z; o[7] += bb.w;
        f16x8 pk;
#pragma unroll
        for (int i = 0; i < 8; ++i) pk[i] = (_Float16)fmaxf(o[i], 0.f);
        *(f16x8*)&Als[lr][l16 << 3] = pk;
    }
    __syncthreads();

    // ---- Phase B: 16-row GEMM tile, NT column tiles split across 4 waves ----
    constexpr int NT = NC / 16;         // 8 (hidden) or 4 (head)
    constexpr int TPW = NT / 4;         // tiles per wave: 2 or 1
    int mr = lane & 15;
    int kq = (lane >> 4) << 3;
    const __half* bh = Bh + (size_t)mr * 128 + kq;
    const __half* bl = Bl + (size_t)mr * 128 + kq;

    f32x4 acc[TPW];
#pragma unroll
    for (int t = 0; t < TPW; ++t) acc[t] = (f32x4){0.f, 0.f, 0.f, 0.f};
#pragma unroll
    for (int kc = 0; kc < 128; kc += 32) {
        f16x8 a = *(const f16x8*)&Als[mr][kq + kc];
#pragma unroll
        for (int t = 0; t < TPW; ++t) {
            int tile = wave * TPW + t;
            f16x8 wh = *(const f16x8*)(bh + (size_t)tile * 16 * 128 + kc);
            f16x8 wl = *(const f16x8*)(bl + (size_t)tile * 16 * 128 + kc);
            acc[t] = __builtin_amdgcn_mfma_f32_16x16x32_f16(a, wh, acc[t], 0, 0, 0);
            acc[t] = __builtin_amdgcn_mfma_f32_16x16x32_f16(a, wl, acc[t], 0, 0, 0);
        }
    }
    int r0 = m0 + ((lane >> 4) << 2);
    int cc = lane & 15;
#pragma unroll
    for (int t = 0; t < TPW; ++t) {
        int tile = wave * TPW + t;
        float bsv = HEAD ? gbias[tile * 16 + cc] : 0.f;
#pragma unroll
        for (int r = 0; r < 4; ++r) {
            if (r0 + r >= n) break;
            size_t idx = (size_t)(r0 + r) * NC + tile * 16 + cc;
            float val = acc[t][r] + bsv;
            if (HEAD)
                ((float*)Cv)[idx] = val;
            else
                ((__half*)Cv)[idx] = __float2half_rn(val);
        }
    }
}

extern "C" void kernel_launch(void* const* d_in, const int* in_sizes, int n_in,
                              void* d_out, int out_size, void* d_ws, size_t ws_size,
                              hipStream_t stream) {
    const float* x  = (const float*)d_in[0];
    const int* ei   = (const int*)d_in[1];
    const float* W0 = (const float*)d_in[2];
    const float* b0 = (const float*)d_in[3];
    const float* W1 = (const float*)d_in[4];
    const float* b1 = (const float*)d_in[5];
    const float* W2 = (const float*)d_in[6];
    const float* b2 = (const float*)d_in[7];
    const float* Wl = (const float*)d_in[8];
    const float* bl = (const float*)d_in[9];
    float* out = (float*)d_out;

    const int N = N_NODES;
    const int E = in_sizes[1] / 2;
    const int* row = ei;
    const int* col = ei + E;
    const int chunk = (((E + NBLK - 1) / NBLK) + 3) & ~3;  // 4-aligned chunks

    char* ws = (char*)d_ws;
    auto alloc = [&](size_t bytes) {
        char* p = ws;
        ws += (bytes + 255) & ~(size_t)255;
        return p;
    };
    int*   hist      = (int*)alloc((size_t)NBINS * NBLK * 4);
    int*   cursorBase= (int*)alloc((size_t)NBINS * NBLK * 4);
    int*   binTotal  = (int*)alloc((size_t)NBINS * 4);
    int*   binBase   = (int*)alloc((size_t)(NBINS + 1) * 4);
    unsigned short* sbuf_src = (unsigned short*)alloc((size_t)E * 2);
    unsigned char*  sbuf_c   = (unsigned char*)alloc((size_t)E);
    int*   row_ptr = (int*)alloc((size_t)(N + 1) * 4);
    float* dinv    = (float*)alloc((size_t)N * 4);
    unsigned short* csr_src = (unsigned short*)alloc((size_t)E * 2);
    __half* h2a    = (__half*)alloc((size_t)N * HID * 2);
    __half* h2b    = (__half*)alloc((size_t)N * HID * 2);
    __half* Wt_h[4];
    __half* Wt_l[4];
    for (int i = 0; i < 3; ++i) {
        Wt_h[i] = (__half*)alloc((size_t)HID * HID * 2);
        Wt_l[i] = (__half*)alloc((size_t)HID * HID * 2);
    }
    Wt_h[3] = (__half*)alloc((size_t)CLS * HID * 2);
    Wt_l[3] = (__half*)alloc((size_t)CLS * HID * 2);

    // K1: histogram + weight split
    hist_wsplit_kernel<<<NBLK, 256, 0, stream>>>(col, hist, W0, W1, W2, Wl,
        Wt_h[0], Wt_l[0], Wt_h[1], Wt_l[1], Wt_h[2], Wt_l[2], Wt_h[3], Wt_l[3], E, chunk);
    // K1.5: per-bin scan over blocks (replaces per-block hist rescan)
    binscan_kernel<<<NBINS, 256, 0, stream>>>(hist, cursorBase, binTotal);
    // K2: bin-sorted scatter
    scatter_kernel<<<NBLK, 256, 0, stream>>>(row, col, binTotal, cursorBase,
        binBase, sbuf_src, sbuf_c, E, chunk);
    // K3: CSR placement fused with GEMM-0 (independent workloads)
    csrplace_gemm0_kernel<<<NBINS + GEMM0_BLOCKS, 256, 0, stream>>>(
        binBase, sbuf_src, sbuf_c, dinv, row_ptr, csr_src,
        x, Wt_h[0], Wt_l[0], h2a, N, E);

    const int fusedBlocks = (N + 15) / 16;  // 3125

    // K4: agg(layer0) + GEMM@W1
    agg_gemm_kernel<128, false><<<fusedBlocks, 256, 0, stream>>>(
        h2a, row_ptr, csr_src, dinv, b0, Wt_h[1], Wt_l[1], nullptr, h2b, N);
    // K5: agg(layer1) + GEMM@W2
    agg_gemm_kernel<128, false><<<fusedBlocks, 256, 0, stream>>>(
        h2b, row_ptr, csr_src, dinv, b1, Wt_h[2], Wt_l[2], nullptr, h2a, N);
    // K6: agg(layer2) + head GEMM@Wl (+bl, fp32 out)
    agg_gemm_kernel<64, true><<<fusedBlocks, 256, 0, stream>>>(
        h2a, row_ptr, csr_src, dinv, b2, Wt_h[3], Wt_l[3], bl, out, N);
}